// Round 3
// baseline (544.427 us; speedup 1.0000x reference)
//
#include <hip/hip_runtime.h>
#include <hip/hip_bf16.h>
#include <cstddef>
#include <cstdint>

typedef unsigned short u16;
typedef __attribute__((ext_vector_type(8))) short bf16x8;   // 8 bf16 in 4 VGPRs
typedef __attribute__((ext_vector_type(4))) float f32x4;
typedef __attribute__((ext_vector_type(8))) unsigned short u16x8;

static __device__ __forceinline__ u16 f2bf(float x) {       // RNE f32->bf16
  unsigned u = __float_as_uint(x);
  u += 0x7fffu + ((u >> 16) & 1u);
  return (u16)(u >> 16);
}
static __device__ __forceinline__ float bflo(unsigned u) { return __uint_as_float(u << 16); }
static __device__ __forceinline__ float bfhi(unsigned u) { return __uint_as_float(u & 0xffff0000u); }

// ---------------------------------------------------------------------------
// Zero the halo (row H, col W) of a padded NHWC buffer [nimg][H+1][W+1][C].
// Producer convs never write the halo; consumers read it as SAME zero-pad.
// ---------------------------------------------------------------------------
__global__ __launch_bounds__(256) void zero_halo(u16* __restrict__ buf,
                                                 int H, int W, int C, int nimg) {
  const int c8n = C >> 3;
  const long long total = (long long)nimg * (W + 1 + H) * c8n;
  const long long i = (long long)blockIdx.x * 256 + threadIdx.x;
  if (i >= total) return;
  const int c8 = (int)(i % c8n);
  long long rem = i / c8n;
  const int p = (int)(rem % (W + 1 + H));
  const int n = (int)(rem / (W + 1 + H));
  int y, x;
  if (p <= W) { y = H; x = p; } else { y = p - (W + 1); x = W; }
  const u16x8 z = {0, 0, 0, 0, 0, 0, 0, 0};
  *(u16x8*)(buf + (((size_t)n * (H + 1) + y) * (W + 1) + x) * C + c8 * 8) = z;
}

// ---------------------------------------------------------------------------
// conv1: 3->64ch, 3x3 s2 SAME, fp32 NCHW in -> bf16 padded-NHWC out.
// Block 256 = 16x16 pixels; all 64 outch per thread; weights in LDS.
// ---------------------------------------------------------------------------
__global__ __launch_bounds__(256) void conv1_s2(
    const float* __restrict__ in,   // [n][3][224][224]
    const float* __restrict__ w,    // [64][3][3][3] OIHW
    const float* __restrict__ bias,
    u16* __restrict__ out) {        // [n][113][113][64] (halo row/col untouched)
  __shared__ float sw[64 * 27];
  __shared__ float sb[64];
  const int tid = threadIdx.x;
  if (tid < 64) sb[tid] = bias[tid];
  for (int i = tid; i < 64 * 27; i += 256) sw[i] = w[i];
  __syncthreads();
  const int n = blockIdx.y;
  const int by = blockIdx.x / 7, bx = blockIdx.x % 7;
  const int oy = by * 16 + (tid >> 4), ox = bx * 16 + (tid & 15);
  const float* ibase = in + (size_t)n * 3 * 224 * 224 + (size_t)(2 * oy) * 224 + 2 * ox;
  float v[27];
  #pragma unroll
  for (int c = 0; c < 3; ++c)
    #pragma unroll
    for (int r = 0; r < 3; ++r)
      #pragma unroll
      for (int s = 0; s < 3; ++s) {
        const int iy = 2 * oy + r, ix = 2 * ox + s;
        float x = 0.f;
        if (iy < 224 && ix < 224) x = ibase[(size_t)c * 224 * 224 + r * 224 + s];
        v[c * 9 + r * 3 + s] = x;
      }
  u16* obase = out + (((size_t)n * 113 + oy) * 113 + ox) * 64;
  #pragma unroll
  for (int kc = 0; kc < 8; ++kc) {
    u16x8 pack;
    #pragma unroll
    for (int k8 = 0; k8 < 8; ++k8) {
      const int k = kc * 8 + k8;
      float a = sb[k];
      const float* wk = &sw[k * 27];
      #pragma unroll
      for (int t = 0; t < 27; ++t) a = fmaf(v[t], wk[t], a);
      pack[k8] = f2bf(fmaxf(a, 0.f));
    }
    *(u16x8*)(obase + kc * 8) = pack;
  }
}

// ---------------------------------------------------------------------------
// Weight repack: OIHW fp32 [K][C][3][3] -> MFMA-fragment-ordered bf16:
//   pw[(((tap*CB + cb)*NB + nbg)*64 + lane)*8 + j] = W[nbg*16 + lane%16]
//        [cb*32 + (lane/16)*8 + j][tap/3][tap%3]
// ---------------------------------------------------------------------------
template<int C, int K>
__global__ __launch_bounds__(256) void pack_w(const float* __restrict__ w,
                                              u16* __restrict__ pw) {
  constexpr int CB = C / 32, NB = K / 16;
  const int idx = blockIdx.x * 256 + threadIdx.x;
  if (idx >= 9 * C * K) return;
  const int j = idx & 7;
  const int L = (idx >> 3) & 63;
  int t = idx >> 9;
  const int nbg = t % NB; t /= NB;
  const int cb = t % CB;
  const int tap = t / CB;
  const int n = nbg * 16 + (L & 15);
  const int c = cb * 32 + ((L >> 4) << 3) + j;
  pw[idx] = f2bf(w[((size_t)n * C + c) * 9 + tap]);
}

// ---------------------------------------------------------------------------
// Implicit-GEMM 3x3 s2 conv over zero-halo padded NHWC bf16, fp32 accum,
// bias+ReLU, padded NHWC bf16 out. mfma_f32_16x16x32_bf16.
// Block 256 thr = 4 waves (2m x 2n); block tile 128px x 128outch;
// wave tile 64px x 64ch = 4x4 fragments -> 16 MFMA per K-step vs 8 loads.
// Fully unrolled tap(9) x cb(C/32) chain: branchless (halo), compiler free
// to hoist loads many steps ahead.
// ---------------------------------------------------------------------------
template<int C, int K, int OH, int OW>
__global__ __launch_bounds__(256) void conv3x3s2_mfma(
    const u16* __restrict__ in,   // [n][2OH+1][2OW+1][C] padded
    const u16* __restrict__ pw,   // packed fragment weights
    const float* __restrict__ bias,
    u16* __restrict__ out) {      // [n][OH+1][OW+1][K] padded
  constexpr int IH = 2 * OH, IW = 2 * OW;
  constexpr int PIW = IW + 1;
  constexpr int P = OH * OW;
  constexpr int BM = 128;
  constexpr int MB = (P + BM - 1) / BM;
  constexpr int CB = C / 32, NB = K / 16;
  const int bm = blockIdx.x % MB;
  const int n = blockIdx.x / MB;
  const int nbh = blockIdx.y;                 // 128-outch group
  const int lane = threadIdx.x & 63, wv = threadIdx.x >> 6;
  const int mh = wv >> 1, nh = wv & 1;
  const int nbase = nbh * 8 + nh * 4;         // first n-frag of this wave
  const int kg = (lane >> 4) << 3;            // channel sub-offset 0/8/16/24

  const u16* ibase = in + (size_t)n * ((IH + 1) * PIW * C);
  int abase[4];
  #pragma unroll
  for (int mf = 0; mf < 4; ++mf) {
    int pm = bm * BM + mh * 64 + mf * 16 + (lane & 15);
    int pc = pm < P ? pm : P - 1;               // clamp: dup loads, guarded store
    int oy = pc / OW, ox = pc % OW;
    abase[mf] = ((2 * oy) * PIW + 2 * ox) * C + kg;
  }

  f32x4 acc[4][4];
  #pragma unroll
  for (int mf = 0; mf < 4; ++mf)
    #pragma unroll
    for (int nf = 0; nf < 4; ++nf) acc[mf][nf] = (f32x4){0.f, 0.f, 0.f, 0.f};

  #pragma unroll
  for (int tap = 0; tap < 9; ++tap) {
    const int r = tap / 3, s = tap - 3 * r;     // constants after unroll
    const int toff = (r * PIW + s) * C;
    #pragma unroll
    for (int cb = 0; cb < CB; ++cb) {
      bf16x8 a[4], b[4];
      #pragma unroll
      for (int mf = 0; mf < 4; ++mf)
        a[mf] = *(const bf16x8*)(ibase + abase[mf] + toff + cb * 32);
      const u16* bp = pw + ((size_t)((tap * CB + cb) * NB + nbase)) * 512 + lane * 8;
      #pragma unroll
      for (int nf = 0; nf < 4; ++nf) b[nf] = *(const bf16x8*)(bp + nf * 512);
      #pragma unroll
      for (int mf = 0; mf < 4; ++mf)
        #pragma unroll
        for (int nf = 0; nf < 4; ++nf)
          acc[mf][nf] = __builtin_amdgcn_mfma_f32_16x16x32_bf16(a[mf], b[nf], acc[mf][nf], 0, 0, 0);
    }
  }

  // Epilogue: D col=lane&15 (outch), row=(lane>>4)*4+reg (pixel)
  const int rowg = (lane >> 4) << 2;
  #pragma unroll
  for (int mf = 0; mf < 4; ++mf)
    #pragma unroll
    for (int nf = 0; nf < 4; ++nf) {
      const int ch = (nbase + nf) * 16 + (lane & 15);
      const float bv = bias[ch];
      #pragma unroll
      for (int rr = 0; rr < 4; ++rr) {
        const int pix = bm * BM + mh * 64 + mf * 16 + rowg + rr;
        if (pix < P) {
          const int oy = pix / OW, ox = pix % OW;
          out[(((size_t)n * (OH + 1) + oy) * (OW + 1) + ox) * K + ch] =
              f2bf(fmaxf(acc[mf][nf][rr] + bv, 0.f));
        }
      }
    }
}

// ---------------------------------------------------------------------------
// Global avg pool over 14x14 of padded [nb][15][15][512] bf16 -> feats fp32.
// ---------------------------------------------------------------------------
__global__ __launch_bounds__(256) void avgpool_nhwc(
    const u16* __restrict__ in, float* __restrict__ feats, int n0) {
  const int n = blockIdx.x, t = threadIdx.x;
  const u16* p = in + (size_t)n * (15 * 15 * 512) + t * 2;
  float s0 = 0.f, s1 = 0.f;
  for (int y = 0; y < 14; ++y)
    #pragma unroll
    for (int x = 0; x < 14; ++x) {
      unsigned u = *(const unsigned*)(p + (size_t)(y * 15 + x) * 512);
      s0 += bflo(u);
      s1 += bfhi(u);
    }
  float* f = feats + (size_t)(n0 + n) * 1024;
  f[2 * t] = s0 * (1.f / 196.f);
  f[2 * t + 1] = s1 * (1.f / 196.f);
}

// ---------------------------------------------------------------------------
// Text branch: masked mean of embedding rows. One block per batch row.
// ---------------------------------------------------------------------------
__global__ __launch_bounds__(256) void embed_mean_kernel(
    const int* __restrict__ seq, const int* __restrict__ len,
    const float* __restrict__ emb, float* __restrict__ means) {
  const int b = blockIdx.x;
  const int L = len[b];
  const int d = threadIdx.x;
  float a0 = 0.f, a1 = 0.f;
  for (int s = 0; s < L; ++s) {
    const float* e = emb + (size_t)seq[b * 128 + s] * 512;
    a0 += e[d];
    a1 += e[d + 256];
  }
  const float inv = 1.f / (float)L;
  means[b * 512 + d] = a0 * inv;
  means[b * 512 + d + 256] = a1 * inv;
}

// ---------------------------------------------------------------------------
// Small FC (fp32): out[m][col] = act(x[m] . W[:,col] + b[col]), W [K][N].
// ---------------------------------------------------------------------------
template<int K, int N, bool RELU>
__global__ __launch_bounds__(256) void fc_kernel(
    const float* __restrict__ x, int ldx,
    const float* __restrict__ w, const float* __restrict__ bias,
    float* __restrict__ out, int ldo) {
  __shared__ float row[K];
  const int m = blockIdx.y;
  for (int i = threadIdx.x; i < K; i += 256) row[i] = x[(size_t)m * ldx + i];
  __syncthreads();
  const int col = blockIdx.x * 256 + threadIdx.x;
  if (col < N) {
    float a = bias[col];
    for (int k = 0; k < K; ++k) a = fmaf(row[k], w[(size_t)k * N + col], a);
    out[(size_t)m * ldo + col] = RELU ? fmaxf(a, 0.f) : a;
  }
}

// ---------------------------------------------------------------------------
extern "C" void kernel_launch(void* const* d_in, const int* in_sizes, int n_in,
                              void* d_out, int out_size, void* d_ws, size_t ws_size,
                              hipStream_t stream) {
  const float* images = (const float*)d_in[0];
  const int*   seq    = (const int*)d_in[1];
  const int*   len    = (const int*)d_in[2];
  const float* emb    = (const float*)d_in[4];
  const float* cw1 = (const float*)d_in[5];  const float* cb1 = (const float*)d_in[6];
  const float* cw2 = (const float*)d_in[7];  const float* cb2 = (const float*)d_in[8];
  const float* cw3 = (const float*)d_in[9];  const float* cb3 = (const float*)d_in[10];
  const float* cw4 = (const float*)d_in[11]; const float* cb4 = (const float*)d_in[12];
  const float* rnn_w = (const float*)d_in[13]; const float* rnn_b = (const float*)d_in[14];
  const float* fc1_w = (const float*)d_in[15]; const float* fc1_b = (const float*)d_in[16];
  const float* fc2_w = (const float*)d_in[17]; const float* fc2_b = (const float*)d_in[18];
  const float* clf_w = (const float*)d_in[19]; const float* clf_b = (const float*)d_in[20];
  float* out = (float*)d_out;

  // Padded NHWC buffers (elems/img)
  const size_t A_E = (size_t)113 * 113 * 64;   // conv1 out
  const size_t B_E = (size_t)57 * 57 * 128;    // conv2 out
  const size_t C_E = (size_t)29 * 29 * 256;    // conv3 out
  const size_t D_E = (size_t)15 * 15 * 512;    // conv4 out
  const size_t PW2_E = 9 * 64 * 128, PW3_E = 9 * 128 * 256, PW4_E = 9 * 256 * 512;
  const size_t PER_IMG = (A_E + B_E + C_E + D_E) * 2;
  const size_t FIXED = (PW2_E + PW3_E + PW4_E) * 2 +
                       (size_t)(64 * 512 + 64 * 1024 + 64 * 512 + 64 * 512) * 4;
  int chunk = 64;
  if (ws_size < FIXED + 64 * PER_IMG) {
    size_t avail = (ws_size > FIXED) ? (ws_size - FIXED) : 0;
    size_t c = avail / PER_IMG;
    chunk = (c < 1) ? 1 : (c > 64 ? 64 : (int)c);
  }
  u16* bufA = (u16*)d_ws;
  u16* bufB = bufA + (size_t)chunk * A_E;
  u16* bufC = bufB + (size_t)chunk * B_E;
  u16* bufD = bufC + (size_t)chunk * C_E;
  u16* pw2 = bufD + (size_t)chunk * D_E;
  u16* pw3 = pw2 + PW2_E;
  u16* pw4 = pw3 + PW3_E;
  float* means = (float*)(pw4 + PW4_E);
  float* feats = means + 64 * 512;
  float* h1 = feats + 64 * 1024;
  float* h2 = h1 + 64 * 512;

  // weight repack (tiny)
  pack_w<64, 128><<<(9 * 64 * 128 + 255) / 256, 256, 0, stream>>>(cw2, pw2);
  pack_w<128, 256><<<(9 * 128 * 256 + 255) / 256, 256, 0, stream>>>(cw3, pw3);
  pack_w<256, 512><<<(9 * 256 * 512 + 255) / 256, 256, 0, stream>>>(cw4, pw4);

  // zero halos once (convs never write halo; geometry fixed per buffer)
  {
    long long t1 = (long long)chunk * (113 + 112) * (64 / 8);
    long long t2 = (long long)chunk * (57 + 56) * (128 / 8);
    long long t3 = (long long)chunk * (29 + 28) * (256 / 8);
    zero_halo<<<(int)((t1 + 255) / 256), 256, 0, stream>>>(bufA, 112, 112, 64, chunk);
    zero_halo<<<(int)((t2 + 255) / 256), 256, 0, stream>>>(bufB, 56, 56, 128, chunk);
    zero_halo<<<(int)((t3 + 255) / 256), 256, 0, stream>>>(bufC, 28, 28, 256, chunk);
  }

  // text branch
  embed_mean_kernel<<<64, 256, 0, stream>>>(seq, len, emb, means);
  fc_kernel<512, 512, false><<<dim3(2, 64), 256, 0, stream>>>(
      means, 512, rnn_w, rnn_b, feats + 512, 1024);

  // image branch
  for (int n0 = 0; n0 < 64; n0 += chunk) {
    int nb = 64 - n0; if (nb > chunk) nb = chunk;
    conv1_s2<<<dim3(49, nb), 256, 0, stream>>>(
        images + (size_t)n0 * 3 * 224 * 224, cw1, cb1, bufA);
    conv3x3s2_mfma<64, 128, 56, 56><<<dim3(25 * nb, 1), 256, 0, stream>>>(
        bufA, pw2, cb2, bufB);
    conv3x3s2_mfma<128, 256, 28, 28><<<dim3(7 * nb, 2), 256, 0, stream>>>(
        bufB, pw3, cb3, bufC);
    conv3x3s2_mfma<256, 512, 14, 14><<<dim3(2 * nb, 4), 256, 0, stream>>>(
        bufC, pw4, cb4, bufD);
    avgpool_nhwc<<<nb, 256, 0, stream>>>(bufD, feats, n0);
  }

  // head
  fc_kernel<1024, 512, true ><<<dim3(2, 64), 256, 0, stream>>>(feats, 1024, fc1_w, fc1_b, h1, 512);
  fc_kernel<512,  512, true ><<<dim3(2, 64), 256, 0, stream>>>(h1,    512,  fc2_w, fc2_b, h2, 512);
  fc_kernel<512, 1000, false><<<dim3(4, 64), 256, 0, stream>>>(h2,    512,  clf_w, clf_b, out, 1000);
}